// Round 1
// baseline (2936.193 us; speedup 1.0000x reference)
//
#include <hip/hip_runtime.h>
#include <math.h>

constexpr int IN_F  = 128;
constexpr int OUT_F = 64;
constexpr int HEADS = 4;
constexpr int COLS  = HEADS * OUT_F;   // 256
constexpr float ALPHA = 0.2f;

// ---------------------------------------------------------------------------
// K1: xt[n, h*64+o] = sum_i x[n,i] * W[h,i,o]
// tile: 64 rows x 64 cols (one head per blockIdx.y). x tile staged transposed
// in LDS; W rows read via L1 (32KB per head, cache resident).
// ---------------------------------------------------------------------------
__global__ __launch_bounds__(256) void k_gemm(const float* __restrict__ x,
                                              const float* __restrict__ W,
                                              float* __restrict__ xt, int n) {
  __shared__ float xs[128][72];   // [i][r], padded
  const int h = blockIdx.y;
  const int rbase = blockIdx.x * 64;
  const int t = threadIdx.x;

  // stage x[rbase .. rbase+63][0..127] -> xs[i][r]
  for (int c = t; c < 2048; c += 256) {     // 2048 float4 chunks
    int r  = c >> 5;                        // 32 chunks per row
    int i4 = (c & 31) << 2;
    int row = rbase + r;
    float4 v = make_float4(0.f, 0.f, 0.f, 0.f);
    if (row < n) v = *(const float4*)(x + (size_t)row * IN_F + i4);
    xs[i4 + 0][r] = v.x;
    xs[i4 + 1][r] = v.y;
    xs[i4 + 2][r] = v.z;
    xs[i4 + 3][r] = v.w;
  }
  __syncthreads();

  const int c0 = (t & 15) << 2;   // col within head: 0..63
  const int r0 = (t >> 4) << 2;   // row within tile: 0..63
  float acc[4][4] = {};
  const float* Wh = W + (size_t)h * IN_F * OUT_F;

  #pragma unroll 4
  for (int i = 0; i < 128; ++i) {
    float4 wv = *(const float4*)(Wh + i * OUT_F + c0);
    float4 xv = *(const float4*)(&xs[i][r0]);
    acc[0][0] += xv.x * wv.x; acc[0][1] += xv.x * wv.y; acc[0][2] += xv.x * wv.z; acc[0][3] += xv.x * wv.w;
    acc[1][0] += xv.y * wv.x; acc[1][1] += xv.y * wv.y; acc[1][2] += xv.y * wv.z; acc[1][3] += xv.y * wv.w;
    acc[2][0] += xv.z * wv.x; acc[2][1] += xv.z * wv.y; acc[2][2] += xv.z * wv.z; acc[2][3] += xv.z * wv.w;
    acc[3][0] += xv.w * wv.x; acc[3][1] += xv.w * wv.y; acc[3][2] += xv.w * wv.z; acc[3][3] += xv.w * wv.w;
  }

  for (int rr = 0; rr < 4; ++rr) {
    int row = rbase + r0 + rr;
    if (row < n) {
      *(float4*)(xt + (size_t)row * COLS + h * OUT_F + c0) =
          make_float4(acc[rr][0], acc[rr][1], acc[rr][2], acc[rr][3]);
    }
  }
}

// ---------------------------------------------------------------------------
// K2: s_src[n,h] = dot(xt[n,h,:], a[h,0:64]);  s_dst[n,h] = dot(xt[n,h,:], a[h,64:128])
// one wave per node; lane l covers cols l*4..l*4+3; 16-lane reduce per head.
// ---------------------------------------------------------------------------
__global__ __launch_bounds__(256) void k_scores(const float* __restrict__ xt,
                                                const float* __restrict__ a,
                                                float* __restrict__ s_src,
                                                float* __restrict__ s_dst, int n) {
  int node = (blockIdx.x * 256 + threadIdx.x) >> 6;
  int lane = threadIdx.x & 63;
  if (node >= n) return;
  int h = lane >> 4;
  int o = (lane & 15) << 2;
  float4 xv = *(const float4*)(xt + (size_t)node * COLS + lane * 4);
  float4 as = *(const float4*)(a + h * 128 + o);
  float4 ad = *(const float4*)(a + h * 128 + 64 + o);
  float ps = xv.x * as.x + xv.y * as.y + xv.z * as.z + xv.w * as.w;
  float pd = xv.x * ad.x + xv.y * ad.y + xv.z * ad.z + xv.w * ad.w;
  #pragma unroll
  for (int m = 1; m < 16; m <<= 1) {
    ps += __shfl_xor(ps, m);
    pd += __shfl_xor(pd, m);
  }
  if ((lane & 15) == 0) {
    s_src[node * 4 + h] = ps;
    s_dst[node * 4 + h] = pd;
  }
}

// ---------------------------------------------------------------------------
// K3: per edge: p[h] = exp(leaky_relu(s_src[src,h] + s_dst[dst,h]))
//     store p, atomic-accumulate sum_exp[dst,h].
// (segment_max skipped: e ~ N(0,1), exp safe; softmax shift-invariant)
// ---------------------------------------------------------------------------
__global__ __launch_bounds__(256) void k_edge1(const int* __restrict__ ei,
                                               const float* __restrict__ s_src,
                                               const float* __restrict__ s_dst,
                                               float* __restrict__ P,
                                               float* __restrict__ sum_exp, int E) {
  int e = blockIdx.x * 256 + threadIdx.x;
  if (e >= E) return;
  int src = ei[e];
  int dst = ei[E + e];
  float4 ss = *(const float4*)(s_src + (size_t)src * 4);
  float4 sd = *(const float4*)(s_dst + (size_t)dst * 4);
  float4 p;
  float v;
  v = ss.x + sd.x; v = v >= 0.f ? v : ALPHA * v; p.x = __expf(v);
  v = ss.y + sd.y; v = v >= 0.f ? v : ALPHA * v; p.y = __expf(v);
  v = ss.z + sd.z; v = v >= 0.f ? v : ALPHA * v; p.z = __expf(v);
  v = ss.w + sd.w; v = v >= 0.f ? v : ALPHA * v; p.w = __expf(v);
  *(float4*)(P + (size_t)e * 4) = p;
  float* se = sum_exp + (size_t)dst * 4;
  atomicAdd(se + 0, p.x);
  atomicAdd(se + 1, p.y);
  atomicAdd(se + 2, p.z);
  atomicAdd(se + 3, p.w);
}

// ---------------------------------------------------------------------------
// K4: per edge (one wave): att[h] = p[h]/(sum_exp[dst,h]+1e-10);
//     out[dst, :] += att[h] * xt[src, :]   (256 f32 atomics / edge)
// ---------------------------------------------------------------------------
__global__ __launch_bounds__(256) void k_edge2(const int* __restrict__ ei,
                                               const float* __restrict__ P,
                                               const float* __restrict__ sum_exp,
                                               const float* __restrict__ xt,
                                               float* __restrict__ out, int E) {
  int e = (blockIdx.x * 256 + threadIdx.x) >> 6;
  if (e >= E) return;
  int lane = threadIdx.x & 63;
  int src = ei[e];
  int dst = ei[E + e];
  int h = lane >> 4;
  float att = P[(size_t)e * 4 + h] / (sum_exp[(size_t)dst * 4 + h] + 1e-10f);
  float4 xv = *(const float4*)(xt + (size_t)src * COLS + lane * 4);
  float* op = out + (size_t)dst * COLS + lane * 4;
  atomicAdd(op + 0, att * xv.x);
  atomicAdd(op + 1, att * xv.y);
  atomicAdd(op + 2, att * xv.z);
  atomicAdd(op + 3, att * xv.w);
}

// ---------------------------------------------------------------------------
extern "C" void kernel_launch(void* const* d_in, const int* in_sizes, int n_in,
                              void* d_out, int out_size, void* d_ws, size_t ws_size,
                              hipStream_t stream) {
  const float* x  = (const float*)d_in[0];
  const int*   ei = (const int*)d_in[1];
  const float* W  = (const float*)d_in[2];
  const float* a  = (const float*)d_in[3];
  float* out = (float*)d_out;

  const int n = in_sizes[0] / IN_F;   // 50000
  const int E = in_sizes[1] / 2;      // 800000

  char* ws = (char*)d_ws;
  size_t off = 0;
  float* xt = (float*)(ws + off);      off += (size_t)n * COLS * 4;   // 51.2 MB
  float* s_src = (float*)(ws + off);   off += (size_t)n * 4 * 4;      // 0.8 MB
  float* s_dst = (float*)(ws + off);   off += (size_t)n * 4 * 4;      // 0.8 MB
  float* P = (float*)(ws + off);       off += (size_t)E * 4 * 4;      // 12.8 MB
  float* sum_exp = (float*)(ws + off); off += (size_t)n * 4 * 4;      // 0.8 MB

  hipMemsetAsync(out, 0, (size_t)out_size * 4, stream);
  hipMemsetAsync(sum_exp, 0, (size_t)n * 4 * 4, stream);

  dim3 g1((n + 63) / 64, HEADS);
  k_gemm<<<g1, 256, 0, stream>>>(x, W, xt, n);

  k_scores<<<(n + 3) / 4, 256, 0, stream>>>(xt, a, s_src, s_dst, n);

  k_edge1<<<(E + 255) / 256, 256, 0, stream>>>(ei, s_src, s_dst, P, sum_exp, E);

  k_edge2<<<(E + 3) / 4, 256, 0, stream>>>(ei, P, sum_exp, xt, out, E);
}

// Round 2
// 404.693 us; speedup vs baseline: 7.2554x; 7.2554x over previous
//
#include <hip/hip_runtime.h>
#include <math.h>

constexpr int IN_F  = 128;
constexpr int OUT_F = 64;
constexpr int HEADS = 4;
constexpr int COLS  = HEADS * OUT_F;   // 256
constexpr float ALPHA = 0.2f;

// ---------------------------------------------------------------------------
// K1: xt[n, h*64+o] = sum_i x[n,i] * W[h,i,o]
// ---------------------------------------------------------------------------
__global__ __launch_bounds__(256) void k_gemm(const float* __restrict__ x,
                                              const float* __restrict__ W,
                                              float* __restrict__ xt, int n) {
  __shared__ float xs[128][72];   // [i][r], padded
  const int h = blockIdx.y;
  const int rbase = blockIdx.x * 64;
  const int t = threadIdx.x;

  for (int c = t; c < 2048; c += 256) {
    int r  = c >> 5;
    int i4 = (c & 31) << 2;
    int row = rbase + r;
    float4 v = make_float4(0.f, 0.f, 0.f, 0.f);
    if (row < n) v = *(const float4*)(x + (size_t)row * IN_F + i4);
    xs[i4 + 0][r] = v.x;
    xs[i4 + 1][r] = v.y;
    xs[i4 + 2][r] = v.z;
    xs[i4 + 3][r] = v.w;
  }
  __syncthreads();

  const int c0 = (t & 15) << 2;
  const int r0 = (t >> 4) << 2;
  float acc[4][4] = {};
  const float* Wh = W + (size_t)h * IN_F * OUT_F;

  #pragma unroll 4
  for (int i = 0; i < 128; ++i) {
    float4 wv = *(const float4*)(Wh + i * OUT_F + c0);
    float4 xv = *(const float4*)(&xs[i][r0]);
    acc[0][0] += xv.x * wv.x; acc[0][1] += xv.x * wv.y; acc[0][2] += xv.x * wv.z; acc[0][3] += xv.x * wv.w;
    acc[1][0] += xv.y * wv.x; acc[1][1] += xv.y * wv.y; acc[1][2] += xv.y * wv.z; acc[1][3] += xv.y * wv.w;
    acc[2][0] += xv.z * wv.x; acc[2][1] += xv.z * wv.y; acc[2][2] += xv.z * wv.z; acc[2][3] += xv.z * wv.w;
    acc[3][0] += xv.w * wv.x; acc[3][1] += xv.w * wv.y; acc[3][2] += xv.w * wv.z; acc[3][3] += xv.w * wv.w;
  }

  for (int rr = 0; rr < 4; ++rr) {
    int row = rbase + r0 + rr;
    if (row < n) {
      *(float4*)(xt + (size_t)row * COLS + h * OUT_F + c0) =
          make_float4(acc[rr][0], acc[rr][1], acc[rr][2], acc[rr][3]);
    }
  }
}

// ---------------------------------------------------------------------------
// K2: per-node score projections
// ---------------------------------------------------------------------------
__global__ __launch_bounds__(256) void k_scores(const float* __restrict__ xt,
                                                const float* __restrict__ a,
                                                float* __restrict__ s_src,
                                                float* __restrict__ s_dst, int n) {
  int node = (blockIdx.x * 256 + threadIdx.x) >> 6;
  int lane = threadIdx.x & 63;
  if (node >= n) return;
  int h = lane >> 4;
  int o = (lane & 15) << 2;
  float4 xv = *(const float4*)(xt + (size_t)node * COLS + lane * 4);
  float4 as = *(const float4*)(a + h * 128 + o);
  float4 ad = *(const float4*)(a + h * 128 + 64 + o);
  float ps = xv.x * as.x + xv.y * as.y + xv.z * as.z + xv.w * as.w;
  float pd = xv.x * ad.x + xv.y * ad.y + xv.z * ad.z + xv.w * ad.w;
  #pragma unroll
  for (int m = 1; m < 16; m <<= 1) {
    ps += __shfl_xor(ps, m);
    pd += __shfl_xor(pd, m);
  }
  if ((lane & 15) == 0) {
    s_src[node * 4 + h] = ps;
    s_dst[node * 4 + h] = pd;
  }
}

// ---------------------------------------------------------------------------
// CSR build: histogram -> scan -> scatter
// ---------------------------------------------------------------------------
__global__ __launch_bounds__(256) void k_deg(const int* __restrict__ ei,
                                             int* __restrict__ deg, int E) {
  int e = blockIdx.x * 256 + threadIdx.x;
  if (e >= E) return;
  atomicAdd(&deg[ei[E + e]], 1);
}

// single-block exclusive scan over n (<= a few 100k) elements
__global__ __launch_bounds__(1024) void k_scan(const int* __restrict__ deg,
                                               int* __restrict__ start,
                                               int* __restrict__ cursor, int n) {
  __shared__ int smem[1024];
  __shared__ int carry_s;
  if (threadIdx.x == 0) carry_s = 0;
  __syncthreads();
  for (int base = 0; base < n; base += 1024) {
    int i = base + (int)threadIdx.x;
    int v = (i < n) ? deg[i] : 0;
    smem[threadIdx.x] = v;
    __syncthreads();
    #pragma unroll
    for (int ofs = 1; ofs < 1024; ofs <<= 1) {
      int t = (threadIdx.x >= (unsigned)ofs) ? smem[threadIdx.x - ofs] : 0;
      __syncthreads();
      smem[threadIdx.x] += t;
      __syncthreads();
    }
    int excl = carry_s + smem[threadIdx.x] - v;
    if (i < n) { start[i] = excl; cursor[i] = excl; }
    __syncthreads();
    if (threadIdx.x == 1023) carry_s += smem[1023];
    __syncthreads();
  }
}

__global__ __launch_bounds__(256) void k_scatter(const int* __restrict__ ei,
                                                 int* __restrict__ cursor,
                                                 int* __restrict__ csr_src, int E) {
  int e = blockIdx.x * 256 + threadIdx.x;
  if (e >= E) return;
  int src = ei[e];
  int dst = ei[E + e];
  int pos = atomicAdd(&cursor[dst], 1);
  csr_src[pos] = src;
}

// ---------------------------------------------------------------------------
// K4: one wave per dst node. Fused softmax-denominator + weighted aggregation:
//   psum   = sum_e exp(lrelu(s_src[src]+s_dst[dst]))       (per head)
//   acc    = sum_e p_e * xt[src, :]
//   out    = acc / (psum + 1e-10)
// No atomics; one coalesced 1KB store per node.
// ---------------------------------------------------------------------------
__global__ __launch_bounds__(256) void k_aggr(const int* __restrict__ csr_src,
                                              const int* __restrict__ start,
                                              const int* __restrict__ deg,
                                              const float* __restrict__ s_src,
                                              const float* __restrict__ s_dst,
                                              const float* __restrict__ xt,
                                              float* __restrict__ out, int n) {
  int node = (blockIdx.x * 256 + threadIdx.x) >> 6;
  if (node >= n) return;
  int lane = threadIdx.x & 63;
  int h = lane >> 4;

  int s = start[node];
  int e = s + deg[node];
  float sd = s_dst[(size_t)node * 4 + h];

  float4 acc = make_float4(0.f, 0.f, 0.f, 0.f);
  float psum = 0.f;

  int src_next = (s < e) ? csr_src[s] : 0;
  for (int j = s; j < e; ++j) {
    int src = src_next;
    if (j + 1 < e) src_next = csr_src[j + 1];
    float v = s_src[(size_t)src * 4 + h] + sd;
    v = v >= 0.f ? v : ALPHA * v;
    float p = __expf(v);
    psum += p;
    float4 xv = *(const float4*)(xt + (size_t)src * COLS + lane * 4);
    acc.x += p * xv.x;
    acc.y += p * xv.y;
    acc.z += p * xv.z;
    acc.w += p * xv.w;
  }

  float inv = 1.f / (psum + 1e-10f);
  acc.x *= inv; acc.y *= inv; acc.z *= inv; acc.w *= inv;
  *(float4*)(out + (size_t)node * COLS + lane * 4) = acc;
}

// ---------------------------------------------------------------------------
extern "C" void kernel_launch(void* const* d_in, const int* in_sizes, int n_in,
                              void* d_out, int out_size, void* d_ws, size_t ws_size,
                              hipStream_t stream) {
  const float* x  = (const float*)d_in[0];
  const int*   ei = (const int*)d_in[1];
  const float* W  = (const float*)d_in[2];
  const float* a  = (const float*)d_in[3];
  float* out = (float*)d_out;

  const int n = in_sizes[0] / IN_F;   // 50000
  const int E = in_sizes[1] / 2;      // 800000

  char* ws = (char*)d_ws;
  size_t off = 0;
  float* xt = (float*)(ws + off);      off += (size_t)n * COLS * 4;   // 51.2 MB
  float* s_src = (float*)(ws + off);   off += (size_t)n * 4 * 4;      // 0.8 MB
  float* s_dst = (float*)(ws + off);   off += (size_t)n * 4 * 4;      // 0.8 MB
  int* deg = (int*)(ws + off);         off += (size_t)n * 4;          // 0.2 MB
  int* start = (int*)(ws + off);       off += (size_t)n * 4;          // 0.2 MB
  int* cursor = (int*)(ws + off);      off += (size_t)n * 4;          // 0.2 MB
  int* csr_src = (int*)(ws + off);     off += (size_t)E * 4;          // 3.2 MB

  hipMemsetAsync(deg, 0, (size_t)n * 4, stream);

  dim3 g1((n + 63) / 64, HEADS);
  k_gemm<<<g1, 256, 0, stream>>>(x, W, xt, n);

  k_scores<<<(n + 3) / 4, 256, 0, stream>>>(xt, a, s_src, s_dst, n);

  k_deg<<<(E + 255) / 256, 256, 0, stream>>>(ei, deg, E);

  k_scan<<<1, 1024, 0, stream>>>(deg, start, cursor, n);

  k_scatter<<<(E + 255) / 256, 256, 0, stream>>>(ei, cursor, csr_src, E);

  k_aggr<<<(n + 3) / 4, 256, 0, stream>>>(csr_src, start, deg, s_src, s_dst, xt, out, n);
}

// Round 3
// 306.053 us; speedup vs baseline: 9.5938x; 1.3223x over previous
//
#include <hip/hip_runtime.h>
#include <math.h>

constexpr int IN_F  = 128;
constexpr int OUT_F = 64;
constexpr int HEADS = 4;
constexpr int COLS  = HEADS * OUT_F;   // 256
constexpr float ALPHA = 0.2f;

__device__ inline unsigned short f2bf(float f) {   // round-to-nearest-even
  unsigned int u = __float_as_uint(f);
  u += 0x7FFF + ((u >> 16) & 1);
  return (unsigned short)(u >> 16);
}
__device__ inline float bf2f(unsigned short s) {
  return __uint_as_float((unsigned int)s << 16);
}

// ---------------------------------------------------------------------------
// K1 (fused): xt = x @ W per head; writes bf16 feature table xtb AND the
// per-node score projections s_src/s_dst (epilogue shfl reduce) — no f32 xt.
// ---------------------------------------------------------------------------
__global__ __launch_bounds__(256) void k_gemm(const float* __restrict__ x,
                                              const float* __restrict__ W,
                                              const float* __restrict__ a,
                                              unsigned short* __restrict__ xtb,
                                              float* __restrict__ s_src,
                                              float* __restrict__ s_dst, int n) {
  __shared__ float xs[128][72];   // [i][r], padded
  const int h = blockIdx.y;
  const int rbase = blockIdx.x * 64;
  const int t = threadIdx.x;

  for (int c = t; c < 2048; c += 256) {
    int r  = c >> 5;
    int i4 = (c & 31) << 2;
    int row = rbase + r;
    float4 v = make_float4(0.f, 0.f, 0.f, 0.f);
    if (row < n) v = *(const float4*)(x + (size_t)row * IN_F + i4);
    xs[i4 + 0][r] = v.x;
    xs[i4 + 1][r] = v.y;
    xs[i4 + 2][r] = v.z;
    xs[i4 + 3][r] = v.w;
  }
  __syncthreads();

  const int c0 = (t & 15) << 2;   // col within head
  const int r0 = (t >> 4) << 2;   // row within tile
  float acc[4][4] = {};
  const float* Wh = W + (size_t)h * IN_F * OUT_F;

  #pragma unroll 4
  for (int i = 0; i < 128; ++i) {
    float4 wv = *(const float4*)(Wh + i * OUT_F + c0);
    float4 xv = *(const float4*)(&xs[i][r0]);
    acc[0][0] += xv.x * wv.x; acc[0][1] += xv.x * wv.y; acc[0][2] += xv.x * wv.z; acc[0][3] += xv.x * wv.w;
    acc[1][0] += xv.y * wv.x; acc[1][1] += xv.y * wv.y; acc[1][2] += xv.y * wv.z; acc[1][3] += xv.y * wv.w;
    acc[2][0] += xv.z * wv.x; acc[2][1] += xv.z * wv.y; acc[2][2] += xv.z * wv.z; acc[2][3] += xv.z * wv.w;
    acc[3][0] += xv.w * wv.x; acc[3][1] += xv.w * wv.y; acc[3][2] += xv.w * wv.z; acc[3][3] += xv.w * wv.w;
  }

  // epilogue A: bf16 feature table
  for (int rr = 0; rr < 4; ++rr) {
    int row = rbase + r0 + rr;
    if (row < n) {
      ushort4 o;
      o.x = f2bf(acc[rr][0]); o.y = f2bf(acc[rr][1]);
      o.z = f2bf(acc[rr][2]); o.w = f2bf(acc[rr][3]);
      *(ushort4*)(xtb + (size_t)row * COLS + h * OUT_F + c0) = o;
    }
  }

  // epilogue B: score projections. thread-partial dot, 16-lane shfl reduce.
  float4 as = *(const float4*)(a + h * 128 + c0);
  float4 ad = *(const float4*)(a + h * 128 + 64 + c0);
  float ps[4], pd[4];
  #pragma unroll
  for (int rr = 0; rr < 4; ++rr) {
    ps[rr] = acc[rr][0] * as.x + acc[rr][1] * as.y + acc[rr][2] * as.z + acc[rr][3] * as.w;
    pd[rr] = acc[rr][0] * ad.x + acc[rr][1] * ad.y + acc[rr][2] * ad.z + acc[rr][3] * ad.w;
  }
  #pragma unroll
  for (int m = 1; m < 16; m <<= 1) {
    #pragma unroll
    for (int rr = 0; rr < 4; ++rr) {
      ps[rr] += __shfl_xor(ps[rr], m);
      pd[rr] += __shfl_xor(pd[rr], m);
    }
  }
  if ((t & 15) == 0) {
    #pragma unroll
    for (int rr = 0; rr < 4; ++rr) {
      int row = rbase + r0 + rr;
      if (row < n) {
        s_src[(size_t)row * 4 + h] = ps[rr];
        s_dst[(size_t)row * 4 + h] = pd[rr];
      }
    }
  }
}

// ---------------------------------------------------------------------------
// CSR build: histogram -> scan -> scatter
// ---------------------------------------------------------------------------
__global__ __launch_bounds__(256) void k_deg(const int* __restrict__ ei,
                                             int* __restrict__ deg, int E) {
  int e = blockIdx.x * 256 + threadIdx.x;
  if (e >= E) return;
  atomicAdd(&deg[ei[E + e]], 1);
}

// single-block scan, shfl-based (3 barriers per 1024-chunk)
__global__ __launch_bounds__(1024) void k_scan(const int* __restrict__ deg,
                                               int* __restrict__ start,
                                               int* __restrict__ cursor, int n) {
  __shared__ int wtot[16];
  __shared__ int woff[16];
  const int tid = threadIdx.x;
  const int lane = tid & 63;
  const int wid = tid >> 6;
  int carry = 0;
  for (int base = 0; base < n; base += 1024) {
    int i = base + tid;
    int v = (i < n) ? deg[i] : 0;
    int sc = v;   // inclusive wave scan
    #pragma unroll
    for (int ofs = 1; ofs < 64; ofs <<= 1) {
      int tv = __shfl_up(sc, ofs, 64);
      if (lane >= ofs) sc += tv;
    }
    if (lane == 63) wtot[wid] = sc;
    __syncthreads();
    if (wid == 0) {
      int wv = (lane < 16) ? wtot[lane] : 0;
      int sw = wv;
      #pragma unroll
      for (int ofs = 1; ofs < 16; ofs <<= 1) {
        int tv = __shfl_up(sw, ofs, 64);
        if (lane >= ofs) sw += tv;
      }
      if (lane < 16) woff[lane] = sw - wv;   // exclusive
    }
    __syncthreads();
    int excl = carry + woff[wid] + (sc - v);
    if (i < n) { start[i] = excl; cursor[i] = excl; }
    carry += woff[15] + wtot[15];
    __syncthreads();
  }
}

__global__ __launch_bounds__(256) void k_scatter(const int* __restrict__ ei,
                                                 int* __restrict__ cursor,
                                                 int* __restrict__ csr_src, int E) {
  int e = blockIdx.x * 256 + threadIdx.x;
  if (e >= E) return;
  int src = ei[e];
  int dst = ei[E + e];
  int pos = atomicAdd(&cursor[dst], 1);
  csr_src[pos] = src;
}

// ---------------------------------------------------------------------------
// K4: one wave per dst node; bf16 feature gathers (512B/edge).
// ---------------------------------------------------------------------------
__global__ __launch_bounds__(256) void k_aggr(const int* __restrict__ csr_src,
                                              const int* __restrict__ start,
                                              const int* __restrict__ deg,
                                              const float* __restrict__ s_src,
                                              const float* __restrict__ s_dst,
                                              const unsigned short* __restrict__ xtb,
                                              float* __restrict__ out, int n) {
  int node = (blockIdx.x * 256 + threadIdx.x) >> 6;
  if (node >= n) return;
  int lane = threadIdx.x & 63;
  int h = lane >> 4;

  int s = start[node];
  int e = s + deg[node];
  float sd = s_dst[(size_t)node * 4 + h];

  float4 acc = make_float4(0.f, 0.f, 0.f, 0.f);
  float psum = 0.f;

  int src_next = (s < e) ? csr_src[s] : 0;
  for (int j = s; j < e; ++j) {
    int src = src_next;
    if (j + 1 < e) src_next = csr_src[j + 1];
    float v = s_src[(size_t)src * 4 + h] + sd;
    v = v >= 0.f ? v : ALPHA * v;
    float p = __expf(v);
    psum += p;
    ushort4 xv = *(const ushort4*)(xtb + (size_t)src * COLS + lane * 4);
    acc.x += p * bf2f(xv.x);
    acc.y += p * bf2f(xv.y);
    acc.z += p * bf2f(xv.z);
    acc.w += p * bf2f(xv.w);
  }

  float inv = 1.f / (psum + 1e-10f);
  acc.x *= inv; acc.y *= inv; acc.z *= inv; acc.w *= inv;
  *(float4*)(out + (size_t)node * COLS + lane * 4) = acc;
}

// ---------------------------------------------------------------------------
extern "C" void kernel_launch(void* const* d_in, const int* in_sizes, int n_in,
                              void* d_out, int out_size, void* d_ws, size_t ws_size,
                              hipStream_t stream) {
  const float* x  = (const float*)d_in[0];
  const int*   ei = (const int*)d_in[1];
  const float* W  = (const float*)d_in[2];
  const float* a  = (const float*)d_in[3];
  float* out = (float*)d_out;

  const int n = in_sizes[0] / IN_F;   // 50000
  const int E = in_sizes[1] / 2;      // 800000

  char* ws = (char*)d_ws;
  size_t off = 0;
  unsigned short* xtb = (unsigned short*)(ws + off); off += (size_t)n * COLS * 2;  // 25.6 MB
  float* s_src = (float*)(ws + off);   off += (size_t)n * 4 * 4;
  float* s_dst = (float*)(ws + off);   off += (size_t)n * 4 * 4;
  int* deg = (int*)(ws + off);         off += (size_t)n * 4;
  int* start = (int*)(ws + off);       off += (size_t)n * 4;
  int* cursor = (int*)(ws + off);      off += (size_t)n * 4;
  int* csr_src = (int*)(ws + off);     off += (size_t)E * 4;

  hipMemsetAsync(deg, 0, (size_t)n * 4, stream);

  dim3 g1((n + 63) / 64, HEADS);
  k_gemm<<<g1, 256, 0, stream>>>(x, W, a, xtb, s_src, s_dst, n);

  k_deg<<<(E + 255) / 256, 256, 0, stream>>>(ei, deg, E);

  k_scan<<<1, 1024, 0, stream>>>(deg, start, cursor, n);

  k_scatter<<<(E + 255) / 256, 256, 0, stream>>>(ei, cursor, csr_src, E);

  k_aggr<<<(n + 3) / 4, 256, 0, stream>>>(csr_src, start, deg, s_src, s_dst, xtb, out, n);
}

// Round 4
// 240.061 us; speedup vs baseline: 12.2310x; 1.2749x over previous
//
#include <hip/hip_runtime.h>
#include <math.h>

constexpr int IN_F  = 128;
constexpr int OUT_F = 64;
constexpr int HEADS = 4;
constexpr int COLS  = HEADS * OUT_F;   // 256
constexpr float ALPHA = 0.2f;

__device__ inline unsigned short f2bf(float f) {   // round-to-nearest-even
  unsigned int u = __float_as_uint(f);
  u += 0x7FFF + ((u >> 16) & 1);
  return (unsigned short)(u >> 16);
}
__device__ inline float bf2f(unsigned short s) {
  return __uint_as_float((unsigned int)s << 16);
}

__device__ inline int wave_incl_scan(int v, int lane) {
  #pragma unroll
  for (int ofs = 1; ofs < 64; ofs <<= 1) {
    int tv = __shfl_up(v, ofs, 64);
    if (lane >= ofs) v += tv;
  }
  return v;
}

// ---------------------------------------------------------------------------
// K1 (fused): xt = x @ W per head -> bf16 table xtb + score projections.
// Transposed LDS tile with column swizzle: x[rbase+r][i] stored at
// xs[i][(r + 4*((i>>2)&15)) & 63]  -> staging writes hit distinct banks
// (2-way max, free), reads stay 16B-aligned ds_read_b128.
// ---------------------------------------------------------------------------
__global__ __launch_bounds__(256) void k_gemm(const float* __restrict__ x,
                                              const float* __restrict__ W,
                                              const float* __restrict__ a,
                                              unsigned short* __restrict__ xtb,
                                              float* __restrict__ s_src,
                                              float* __restrict__ s_dst, int n) {
  __shared__ float xs[128][72];
  const int h = blockIdx.y;
  const int rbase = blockIdx.x * 64;
  const int t = threadIdx.x;

  for (int c = t; c < 2048; c += 256) {
    int r   = c >> 5;          // 0..63
    int i4c = c & 31;          // chunk within row
    int i   = i4c << 2;        // element base
    int row = rbase + r;
    float4 v = make_float4(0.f, 0.f, 0.f, 0.f);
    if (row < n) v = *(const float4*)(x + (size_t)row * IN_F + i);
    int rp = (r + ((i4c & 15) << 2)) & 63;   // swizzled column
    xs[i + 0][rp] = v.x;
    xs[i + 1][rp] = v.y;
    xs[i + 2][rp] = v.z;
    xs[i + 3][rp] = v.w;
  }
  __syncthreads();

  const int c0 = (t & 15) << 2;   // col within head
  const int r0 = (t >> 4) << 2;   // logical row within tile
  float acc[4][4] = {};
  const float* Wh = W + (size_t)h * IN_F * OUT_F;

  #pragma unroll 4
  for (int i = 0; i < 128; ++i) {
    float4 wv = *(const float4*)(Wh + i * OUT_F + c0);
    int pc = (r0 + (((i >> 2) & 15) << 2)) & 63;   // same swizzle on read
    float4 xv = *(const float4*)(&xs[i][pc]);
    acc[0][0] += xv.x * wv.x; acc[0][1] += xv.x * wv.y; acc[0][2] += xv.x * wv.z; acc[0][3] += xv.x * wv.w;
    acc[1][0] += xv.y * wv.x; acc[1][1] += xv.y * wv.y; acc[1][2] += xv.y * wv.z; acc[1][3] += xv.y * wv.w;
    acc[2][0] += xv.z * wv.x; acc[2][1] += xv.z * wv.y; acc[2][2] += xv.z * wv.z; acc[2][3] += xv.z * wv.w;
    acc[3][0] += xv.w * wv.x; acc[3][1] += xv.w * wv.y; acc[3][2] += xv.w * wv.z; acc[3][3] += xv.w * wv.w;
  }

  // epilogue A: bf16 feature table
  for (int rr = 0; rr < 4; ++rr) {
    int row = rbase + r0 + rr;
    if (row < n) {
      ushort4 o;
      o.x = f2bf(acc[rr][0]); o.y = f2bf(acc[rr][1]);
      o.z = f2bf(acc[rr][2]); o.w = f2bf(acc[rr][3]);
      *(ushort4*)(xtb + (size_t)row * COLS + h * OUT_F + c0) = o;
    }
  }

  // epilogue B: score projections (16-lane shfl reduce of acc . a)
  float4 as = *(const float4*)(a + h * 128 + c0);
  float4 ad = *(const float4*)(a + h * 128 + 64 + c0);
  float ps[4], pd[4];
  #pragma unroll
  for (int rr = 0; rr < 4; ++rr) {
    ps[rr] = acc[rr][0] * as.x + acc[rr][1] * as.y + acc[rr][2] * as.z + acc[rr][3] * as.w;
    pd[rr] = acc[rr][0] * ad.x + acc[rr][1] * ad.y + acc[rr][2] * ad.z + acc[rr][3] * ad.w;
  }
  #pragma unroll
  for (int m = 1; m < 16; m <<= 1) {
    #pragma unroll
    for (int rr = 0; rr < 4; ++rr) {
      ps[rr] += __shfl_xor(ps[rr], m);
      pd[rr] += __shfl_xor(pd[rr], m);
    }
  }
  if ((t & 15) == 0) {
    #pragma unroll
    for (int rr = 0; rr < 4; ++rr) {
      int row = rbase + r0 + rr;
      if (row < n) {
        s_src[(size_t)row * 4 + h] = ps[rr];
        s_dst[(size_t)row * 4 + h] = pd[rr];
      }
    }
  }
}

// ---------------------------------------------------------------------------
// CSR build: histogram -> 3-pass scan -> scatter
// ---------------------------------------------------------------------------
__global__ __launch_bounds__(256) void k_deg(const int* __restrict__ ei,
                                             int* __restrict__ deg, int E) {
  int e = blockIdx.x * 256 + threadIdx.x;
  if (e >= E) return;
  atomicAdd(&deg[ei[E + e]], 1);
}

// pass 1: per-block (256 elems) sums
__global__ __launch_bounds__(256) void k_scan_part(const int* __restrict__ deg,
                                                   int* __restrict__ part, int n) {
  __shared__ int wt[4];
  int i = blockIdx.x * 256 + threadIdx.x;
  int lane = threadIdx.x & 63;
  int wid = threadIdx.x >> 6;
  int v = (i < n) ? deg[i] : 0;
  #pragma unroll
  for (int m = 1; m < 64; m <<= 1) v += __shfl_xor(v, m);
  if (lane == 0) wt[wid] = v;
  __syncthreads();
  if (threadIdx.x == 0) part[blockIdx.x] = wt[0] + wt[1] + wt[2] + wt[3];
}

// pass 2: single block, exclusive scan over nb (<=256) partials
__global__ __launch_bounds__(256) void k_scan_top(int* __restrict__ part, int nb) {
  __shared__ int wt[4];
  int t = threadIdx.x;
  int lane = t & 63;
  int wid = t >> 6;
  int v = (t < nb) ? part[t] : 0;
  int incl = wave_incl_scan(v, lane);
  if (lane == 63) wt[wid] = incl;
  __syncthreads();
  int wofs = 0;
  #pragma unroll
  for (int w = 0; w < 4; ++w) wofs += (w < wid) ? wt[w] : 0;
  if (t < nb) part[t] = wofs + incl - v;   // exclusive block offset
}

// pass 3: per-block exclusive scan + block offset -> start/cursor
__global__ __launch_bounds__(256) void k_scan_out(const int* __restrict__ deg,
                                                  const int* __restrict__ part,
                                                  int* __restrict__ start,
                                                  int* __restrict__ cursor, int n) {
  __shared__ int wt[4];
  int i = blockIdx.x * 256 + threadIdx.x;
  int lane = threadIdx.x & 63;
  int wid = threadIdx.x >> 6;
  int v = (i < n) ? deg[i] : 0;
  int incl = wave_incl_scan(v, lane);
  if (lane == 63) wt[wid] = incl;
  __syncthreads();
  int wofs = 0;
  #pragma unroll
  for (int w = 0; w < 4; ++w) wofs += (w < wid) ? wt[w] : 0;
  int excl = part[blockIdx.x] + wofs + incl - v;
  if (i < n) { start[i] = excl; cursor[i] = excl; }
}

__global__ __launch_bounds__(256) void k_scatter(const int* __restrict__ ei,
                                                 int* __restrict__ cursor,
                                                 int* __restrict__ csr_src, int E) {
  int e = blockIdx.x * 256 + threadIdx.x;
  if (e >= E) return;
  int src = ei[e];
  int dst = ei[E + e];
  int pos = atomicAdd(&cursor[dst], 1);
  csr_src[pos] = src;
}

// ---------------------------------------------------------------------------
// K4: one wave per dst node; bf16 feature gathers (512B/edge), fused softmax.
// ---------------------------------------------------------------------------
__global__ __launch_bounds__(256) void k_aggr(const int* __restrict__ csr_src,
                                              const int* __restrict__ start,
                                              const int* __restrict__ deg,
                                              const float* __restrict__ s_src,
                                              const float* __restrict__ s_dst,
                                              const unsigned short* __restrict__ xtb,
                                              float* __restrict__ out, int n) {
  int node = (blockIdx.x * 256 + threadIdx.x) >> 6;
  if (node >= n) return;
  int lane = threadIdx.x & 63;
  int h = lane >> 4;

  int s = start[node];
  int e = s + deg[node];
  float sd = s_dst[(size_t)node * 4 + h];

  float4 acc = make_float4(0.f, 0.f, 0.f, 0.f);
  float psum = 0.f;

  int src_next = (s < e) ? csr_src[s] : 0;
  for (int j = s; j < e; ++j) {
    int src = src_next;
    if (j + 1 < e) src_next = csr_src[j + 1];
    float v = s_src[(size_t)src * 4 + h] + sd;
    v = v >= 0.f ? v : ALPHA * v;
    float p = __expf(v);
    psum += p;
    ushort4 xv = *(const ushort4*)(xtb + (size_t)src * COLS + lane * 4);
    acc.x += p * bf2f(xv.x);
    acc.y += p * bf2f(xv.y);
    acc.z += p * bf2f(xv.z);
    acc.w += p * bf2f(xv.w);
  }

  float inv = 1.f / (psum + 1e-10f);
  acc.x *= inv; acc.y *= inv; acc.z *= inv; acc.w *= inv;
  *(float4*)(out + (size_t)node * COLS + lane * 4) = acc;
}

// ---------------------------------------------------------------------------
extern "C" void kernel_launch(void* const* d_in, const int* in_sizes, int n_in,
                              void* d_out, int out_size, void* d_ws, size_t ws_size,
                              hipStream_t stream) {
  const float* x  = (const float*)d_in[0];
  const int*   ei = (const int*)d_in[1];
  const float* W  = (const float*)d_in[2];
  const float* a  = (const float*)d_in[3];
  float* out = (float*)d_out;

  const int n = in_sizes[0] / IN_F;   // 50000
  const int E = in_sizes[1] / 2;      // 800000
  const int nb = (n + 255) / 256;     // 196 scan blocks

  char* ws = (char*)d_ws;
  size_t off = 0;
  unsigned short* xtb = (unsigned short*)(ws + off); off += (size_t)n * COLS * 2;  // 25.6 MB
  float* s_src = (float*)(ws + off);   off += (size_t)n * 4 * 4;
  float* s_dst = (float*)(ws + off);   off += (size_t)n * 4 * 4;
  int* deg = (int*)(ws + off);         off += (size_t)n * 4;
  int* start = (int*)(ws + off);       off += (size_t)n * 4;
  int* cursor = (int*)(ws + off);      off += (size_t)n * 4;
  int* part = (int*)(ws + off);        off += (size_t)nb * 4;
  int* csr_src = (int*)(ws + off);     off += (size_t)E * 4;

  hipMemsetAsync(deg, 0, (size_t)n * 4, stream);

  dim3 g1((n + 63) / 64, HEADS);
  k_gemm<<<g1, 256, 0, stream>>>(x, W, a, xtb, s_src, s_dst, n);

  k_deg<<<(E + 255) / 256, 256, 0, stream>>>(ei, deg, E);

  k_scan_part<<<nb, 256, 0, stream>>>(deg, part, n);
  k_scan_top<<<1, 256, 0, stream>>>(part, nb);
  k_scan_out<<<nb, 256, 0, stream>>>(deg, part, start, cursor, n);

  k_scatter<<<(E + 255) / 256, 256, 0, stream>>>(ei, cursor, csr_src, E);

  k_aggr<<<(n + 3) / 4, 256, 0, stream>>>(csr_src, start, deg, s_src, s_dst, xtb, out, n);
}

// Round 5
// 206.446 us; speedup vs baseline: 14.2226x; 1.1628x over previous
//
#include <hip/hip_runtime.h>
#include <math.h>

constexpr int IN_F  = 128;
constexpr int OUT_F = 64;
constexpr int HEADS = 4;
constexpr int COLS  = HEADS * OUT_F;   // 256
constexpr float ALPHA = 0.2f;

typedef __attribute__((ext_vector_type(8))) short short8v;   // 8 bf16 = 4 VGPR
typedef __attribute__((ext_vector_type(4))) float f32x4;

__device__ inline unsigned short f2bf(float f) {   // round-to-nearest-even
  unsigned int u = __float_as_uint(f);
  u += 0x7FFF + ((u >> 16) & 1);
  return (unsigned short)(u >> 16);
}
__device__ inline float bf2f(unsigned short s) {
  return __uint_as_float((unsigned int)s << 16);
}

__device__ inline int wave_incl_scan(int v, int lane) {
  #pragma unroll
  for (int ofs = 1; ofs < 64; ofs <<= 1) {
    int tv = __shfl_up(v, ofs, 64);
    if (lane >= ofs) v += tv;
  }
  return v;
}

// ---------------------------------------------------------------------------
// W pre-transpose: W[h][i][o] f32  ->  Wb[h][o][i] bf16  (B^T layout, 64KB)
// ---------------------------------------------------------------------------
__global__ __launch_bounds__(256) void k_wconv(const float* __restrict__ W,
                                               unsigned short* __restrict__ Wb) {
  int idx = blockIdx.x * 256 + threadIdx.x;
  if (idx >= HEADS * IN_F * OUT_F) return;
  int h = idx >> 13;            // /8192
  int o = (idx >> 7) & 63;      // output-layout row
  int i = idx & 127;            // output-layout col (= k)
  Wb[idx] = f2bf(W[(size_t)h * 8192 + i * 64 + o]);
}

// ---------------------------------------------------------------------------
// K1 (MFMA): one block = 64 rows x 256 cols (wave w = head w).
//  - x tile staged as bf16 in LDS, XOR-swizzled (byte ^= (row&7)<<4)
//  - A-frag: lane holds x[m=mi*16+(lane&15)][k=kk*32+(lane>>4)*8 + 0..7]
//  - B-frag: lane holds Wb[h][n=ni*16+(lane&15)][same k]  (contiguous 16B)
//  - D: col = lane&15, row = (lane>>4)*4 + reg                 (m89-verified)
// Epilogue: scores from f32 acc (shfl reduce), bf16 out via LDS, coalesced.
// ---------------------------------------------------------------------------
__global__ __launch_bounds__(256) void k_gemm(const float* __restrict__ x,
                                              const unsigned short* __restrict__ Wb,
                                              const float* __restrict__ a,
                                              unsigned short* __restrict__ xtb,
                                              float* __restrict__ s_src,
                                              float* __restrict__ s_dst, int n) {
  __shared__ unsigned short xls[64 * 128];    // 16KB bf16, swizzled
  __shared__ unsigned short ols[64 * 256];    // 32KB output staging
  const int t = threadIdx.x;
  const int rbase = blockIdx.x * 64;
  const int lane = t & 63;
  const int w = t >> 6;                       // wave id = head

  // stage x tile -> bf16 swizzled LDS
  for (int c = t; c < 2048; c += 256) {
    int row = c >> 5;
    int i4  = c & 31;
    int grow = rbase + row;
    float4 v = make_float4(0.f, 0.f, 0.f, 0.f);
    if (grow < n) v = *(const float4*)(x + (size_t)grow * IN_F + i4 * 4);
    unsigned int p0 = (unsigned int)f2bf(v.x) | ((unsigned int)f2bf(v.y) << 16);
    unsigned int p1 = (unsigned int)f2bf(v.z) | ((unsigned int)f2bf(v.w) << 16);
    int byte = row * 256 + ((i4 * 8) ^ ((row & 7) << 4));
    *(uint2*)((char*)xls + byte) = make_uint2(p0, p1);
  }
  __syncthreads();

  const unsigned short* Wh = Wb + (size_t)w * 8192;
  const int nfix = lane & 15;
  const int kg   = lane >> 4;

  f32x4 acc[4][4] = {};   // [mi][ni]

  #pragma unroll
  for (int kk = 0; kk < 4; ++kk) {
    short8v bfrag[4];
    #pragma unroll
    for (int ni = 0; ni < 4; ++ni)
      bfrag[ni] = *(const short8v*)(Wh + (ni * 16 + nfix) * 128 + kk * 32 + kg * 8);
    #pragma unroll
    for (int mi = 0; mi < 4; ++mi) {
      int m = mi * 16 + nfix;
      int abyte = m * 256 + ((kk * 64 + kg * 16) ^ ((m & 7) << 4));
      short8v afrag = *(const short8v*)((char*)xls + abyte);
      #pragma unroll
      for (int ni = 0; ni < 4; ++ni)
        acc[mi][ni] = __builtin_amdgcn_mfma_f32_16x16x32_bf16(
            afrag, bfrag[ni], acc[mi][ni], 0, 0, 0);
    }
  }

  // epilogue B: score projections from f32 accumulators
  float as[4], ad[4];
  #pragma unroll
  for (int ni = 0; ni < 4; ++ni) {
    as[ni] = a[w * 128 + ni * 16 + nfix];
    ad[ni] = a[w * 128 + 64 + ni * 16 + nfix];
  }
  #pragma unroll
  for (int mi = 0; mi < 4; ++mi) {
    #pragma unroll
    for (int r = 0; r < 4; ++r) {
      float ps = 0.f, pd = 0.f;
      #pragma unroll
      for (int ni = 0; ni < 4; ++ni) {
        ps += acc[mi][ni][r] * as[ni];
        pd += acc[mi][ni][r] * ad[ni];
      }
      #pragma unroll
      for (int m = 1; m < 16; m <<= 1) {
        ps += __shfl_xor(ps, m);
        pd += __shfl_xor(pd, m);
      }
      if ((lane & 15) == 0) {
        int row = rbase + mi * 16 + (kg << 2) + r;
        if (row < n) {
          s_src[(size_t)row * 4 + w] = ps;
          s_dst[(size_t)row * 4 + w] = pd;
        }
      }
    }
  }

  // epilogue A: dump acc (bf16) to LDS, then coalesced 16B stores
  #pragma unroll
  for (int mi = 0; mi < 4; ++mi)
    #pragma unroll
    for (int ni = 0; ni < 4; ++ni)
      #pragma unroll
      for (int r = 0; r < 4; ++r) {
        int row = mi * 16 + (kg << 2) + r;
        int col = (w << 6) + ni * 16 + nfix;
        ols[row * 256 + col] = f2bf(acc[mi][ni][r]);
      }
  __syncthreads();
  for (int c = t; c < 2048; c += 256) {
    int row = c >> 5;
    int ch  = c & 31;
    int grow = rbase + row;
    if (grow < n)
      *(uint4*)(xtb + (size_t)grow * COLS + ch * 8) =
          *(const uint4*)(ols + row * 256 + ch * 8);
  }
}

// ---------------------------------------------------------------------------
// CSR build: histogram -> 3-pass scan -> scatter
// ---------------------------------------------------------------------------
__global__ __launch_bounds__(256) void k_deg(const int* __restrict__ ei,
                                             int* __restrict__ deg, int E) {
  int e = blockIdx.x * 256 + threadIdx.x;
  if (e >= E) return;
  atomicAdd(&deg[ei[E + e]], 1);
}

__global__ __launch_bounds__(256) void k_scan_part(const int* __restrict__ deg,
                                                   int* __restrict__ part, int n) {
  __shared__ int wt[4];
  int i = blockIdx.x * 256 + threadIdx.x;
  int lane = threadIdx.x & 63;
  int wid = threadIdx.x >> 6;
  int v = (i < n) ? deg[i] : 0;
  #pragma unroll
  for (int m = 1; m < 64; m <<= 1) v += __shfl_xor(v, m);
  if (lane == 0) wt[wid] = v;
  __syncthreads();
  if (threadIdx.x == 0) part[blockIdx.x] = wt[0] + wt[1] + wt[2] + wt[3];
}

__global__ __launch_bounds__(256) void k_scan_top(int* __restrict__ part, int nb) {
  __shared__ int wt[4];
  int t = threadIdx.x;
  int lane = t & 63;
  int wid = t >> 6;
  int v = (t < nb) ? part[t] : 0;
  int incl = wave_incl_scan(v, lane);
  if (lane == 63) wt[wid] = incl;
  __syncthreads();
  int wofs = 0;
  #pragma unroll
  for (int w = 0; w < 4; ++w) wofs += (w < wid) ? wt[w] : 0;
  if (t < nb) part[t] = wofs + incl - v;
}

__global__ __launch_bounds__(256) void k_scan_out(const int* __restrict__ deg,
                                                  const int* __restrict__ part,
                                                  int* __restrict__ start,
                                                  int* __restrict__ cursor, int n) {
  __shared__ int wt[4];
  int i = blockIdx.x * 256 + threadIdx.x;
  int lane = threadIdx.x & 63;
  int wid = threadIdx.x >> 6;
  int v = (i < n) ? deg[i] : 0;
  int incl = wave_incl_scan(v, lane);
  if (lane == 63) wt[wid] = incl;
  __syncthreads();
  int wofs = 0;
  #pragma unroll
  for (int w = 0; w < 4; ++w) wofs += (w < wid) ? wt[w] : 0;
  int excl = part[blockIdx.x] + wofs + incl - v;
  if (i < n) { start[i] = excl; cursor[i] = excl; }
}

__global__ __launch_bounds__(256) void k_scatter(const int* __restrict__ ei,
                                                 int* __restrict__ cursor,
                                                 int* __restrict__ csr_src, int E) {
  int e = blockIdx.x * 256 + threadIdx.x;
  if (e >= E) return;
  int src = ei[e];
  int dst = ei[E + e];
  int pos = atomicAdd(&cursor[dst], 1);
  csr_src[pos] = src;
}

// ---------------------------------------------------------------------------
// K4: one wave per dst node; bf16 feature gathers, fused softmax.
// ---------------------------------------------------------------------------
__global__ __launch_bounds__(256) void k_aggr(const int* __restrict__ csr_src,
                                              const int* __restrict__ start,
                                              const int* __restrict__ deg,
                                              const float* __restrict__ s_src,
                                              const float* __restrict__ s_dst,
                                              const unsigned short* __restrict__ xtb,
                                              float* __restrict__ out, int n) {
  int node = (blockIdx.x * 256 + threadIdx.x) >> 6;
  if (node >= n) return;
  int lane = threadIdx.x & 63;
  int h = lane >> 4;

  int s = start[node];
  int e = s + deg[node];
  float sd = s_dst[(size_t)node * 4 + h];

  float4 acc = make_float4(0.f, 0.f, 0.f, 0.f);
  float psum = 0.f;

  int src_next = (s < e) ? csr_src[s] : 0;
  for (int j = s; j < e; ++j) {
    int src = src_next;
    if (j + 1 < e) src_next = csr_src[j + 1];
    float v = s_src[(size_t)src * 4 + h] + sd;
    v = v >= 0.f ? v : ALPHA * v;
    float p = __expf(v);
    psum += p;
    ushort4 xv = *(const ushort4*)(xtb + (size_t)src * COLS + lane * 4);
    acc.x += p * bf2f(xv.x);
    acc.y += p * bf2f(xv.y);
    acc.z += p * bf2f(xv.z);
    acc.w += p * bf2f(xv.w);
  }

  float inv = 1.f / (psum + 1e-10f);
  acc.x *= inv; acc.y *= inv; acc.z *= inv; acc.w *= inv;
  *(float4*)(out + (size_t)node * COLS + lane * 4) = acc;
}

// ---------------------------------------------------------------------------
extern "C" void kernel_launch(void* const* d_in, const int* in_sizes, int n_in,
                              void* d_out, int out_size, void* d_ws, size_t ws_size,
                              hipStream_t stream) {
  const float* x  = (const float*)d_in[0];
  const int*   ei = (const int*)d_in[1];
  const float* W  = (const float*)d_in[2];
  const float* a  = (const float*)d_in[3];
  float* out = (float*)d_out;

  const int n = in_sizes[0] / IN_F;   // 50000
  const int E = in_sizes[1] / 2;      // 800000
  const int nb = (n + 255) / 256;     // scan blocks

  char* ws = (char*)d_ws;
  size_t off = 0;
  unsigned short* xtb = (unsigned short*)(ws + off); off += (size_t)n * COLS * 2;  // 25.6 MB
  unsigned short* Wb  = (unsigned short*)(ws + off); off += (size_t)HEADS * IN_F * OUT_F * 2;
  float* s_src = (float*)(ws + off);   off += (size_t)n * 4 * 4;
  float* s_dst = (float*)(ws + off);   off += (size_t)n * 4 * 4;
  int* deg = (int*)(ws + off);         off += (size_t)n * 4;
  int* start = (int*)(ws + off);       off += (size_t)n * 4;
  int* cursor = (int*)(ws + off);      off += (size_t)n * 4;
  int* part = (int*)(ws + off);        off += (size_t)nb * 4;
  int* csr_src = (int*)(ws + off);     off += (size_t)E * 4;

  hipMemsetAsync(deg, 0, (size_t)n * 4, stream);

  k_wconv<<<(HEADS * IN_F * OUT_F + 255) / 256, 256, 0, stream>>>(W, Wb);

  k_gemm<<<(n + 63) / 64, 256, 0, stream>>>(x, Wb, a, xtb, s_src, s_dst, n);

  k_deg<<<(E + 255) / 256, 256, 0, stream>>>(ei, deg, E);

  k_scan_part<<<nb, 256, 0, stream>>>(deg, part, n);
  k_scan_top<<<1, 256, 0, stream>>>(part, nb);
  k_scan_out<<<nb, 256, 0, stream>>>(deg, part, start, cursor, n);

  k_scatter<<<(E + 255) / 256, 256, 0, stream>>>(ei, cursor, csr_src, E);

  k_aggr<<<(n + 3) / 4, 256, 0, stream>>>(csr_src, start, deg, s_src, s_dst, xtb, out, n);
}

// Round 6
// 203.056 us; speedup vs baseline: 14.4600x; 1.0167x over previous
//
#include <hip/hip_runtime.h>
#include <math.h>

constexpr int IN_F  = 128;
constexpr int OUT_F = 64;
constexpr int HEADS = 4;
constexpr int COLS  = HEADS * OUT_F;   // 256
constexpr float ALPHA = 0.2f;

typedef __attribute__((ext_vector_type(8))) short short8v;   // 8 bf16 = 4 VGPR
typedef __attribute__((ext_vector_type(4))) float f32x4;

__device__ inline unsigned short f2bf(float f) {   // round-to-nearest-even
  unsigned int u = __float_as_uint(f);
  u += 0x7FFF + ((u >> 16) & 1);
  return (unsigned short)(u >> 16);
}
__device__ inline float bf2f(unsigned short s) {
  return __uint_as_float((unsigned int)s << 16);
}

__device__ inline int wave_incl_scan(int v, int lane) {
  #pragma unroll
  for (int ofs = 1; ofs < 64; ofs <<= 1) {
    int tv = __shfl_up(v, ofs, 64);
    if (lane >= ofs) v += tv;
  }
  return v;
}

// ---------------------------------------------------------------------------
// W pre-transpose: W[h][i][o] f32  ->  Wb[h][o][i] bf16  (B^T layout, 64KB)
// ---------------------------------------------------------------------------
__global__ __launch_bounds__(256) void k_wconv(const float* __restrict__ W,
                                               unsigned short* __restrict__ Wb) {
  int idx = blockIdx.x * 256 + threadIdx.x;
  if (idx >= HEADS * IN_F * OUT_F) return;
  int h = idx >> 13;
  int o = (idx >> 7) & 63;
  int i = idx & 127;
  Wb[idx] = f2bf(W[(size_t)h * 8192 + i * 64 + o]);
}

// ---------------------------------------------------------------------------
// K1 (MFMA): one block = 64 rows x 256 cols (wave w = head w).
// ols staging swizzled: byte ^= ((row>>2)&3)<<5 -> kg groups hit disjoint
// bank quartets (2 lanes/bank, free) instead of 8-way conflicts.
// ---------------------------------------------------------------------------
__global__ __launch_bounds__(256) void k_gemm(const float* __restrict__ x,
                                              const unsigned short* __restrict__ Wb,
                                              const float* __restrict__ a,
                                              unsigned short* __restrict__ xtb,
                                              float* __restrict__ s_src,
                                              float* __restrict__ s_dst, int n) {
  __shared__ unsigned short xls[64 * 128];    // 16KB bf16, swizzled
  __shared__ unsigned short ols[64 * 256];    // 32KB output staging, swizzled
  const int t = threadIdx.x;
  const int rbase = blockIdx.x * 64;
  const int lane = t & 63;
  const int w = t >> 6;                       // wave id = head

  // stage x tile -> bf16 swizzled LDS
  for (int c = t; c < 2048; c += 256) {
    int row = c >> 5;
    int i4  = c & 31;
    int grow = rbase + row;
    float4 v = make_float4(0.f, 0.f, 0.f, 0.f);
    if (grow < n) v = *(const float4*)(x + (size_t)grow * IN_F + i4 * 4);
    unsigned int p0 = (unsigned int)f2bf(v.x) | ((unsigned int)f2bf(v.y) << 16);
    unsigned int p1 = (unsigned int)f2bf(v.z) | ((unsigned int)f2bf(v.w) << 16);
    int byte = row * 256 + ((i4 * 8) ^ ((row & 7) << 4));
    *(uint2*)((char*)xls + byte) = make_uint2(p0, p1);
  }
  __syncthreads();

  const unsigned short* Wh = Wb + (size_t)w * 8192;
  const int nfix = lane & 15;
  const int kg   = lane >> 4;

  f32x4 acc[4][4] = {};   // [mi][ni]

  #pragma unroll
  for (int kk = 0; kk < 4; ++kk) {
    short8v bfrag[4];
    #pragma unroll
    for (int ni = 0; ni < 4; ++ni)
      bfrag[ni] = *(const short8v*)(Wh + (ni * 16 + nfix) * 128 + kk * 32 + kg * 8);
    #pragma unroll
    for (int mi = 0; mi < 4; ++mi) {
      int m = mi * 16 + nfix;
      int abyte = m * 256 + ((kk * 64 + kg * 16) ^ ((m & 7) << 4));
      short8v afrag = *(const short8v*)((char*)xls + abyte);
      #pragma unroll
      for (int ni = 0; ni < 4; ++ni)
        acc[mi][ni] = __builtin_amdgcn_mfma_f32_16x16x32_bf16(
            afrag, bfrag[ni], acc[mi][ni], 0, 0, 0);
    }
  }

  // epilogue B: score projections from f32 accumulators
  float as[4], ad[4];
  #pragma unroll
  for (int ni = 0; ni < 4; ++ni) {
    as[ni] = a[w * 128 + ni * 16 + nfix];
    ad[ni] = a[w * 128 + 64 + ni * 16 + nfix];
  }
  #pragma unroll
  for (int mi = 0; mi < 4; ++mi) {
    #pragma unroll
    for (int r = 0; r < 4; ++r) {
      float ps = 0.f, pd = 0.f;
      #pragma unroll
      for (int ni = 0; ni < 4; ++ni) {
        ps += acc[mi][ni][r] * as[ni];
        pd += acc[mi][ni][r] * ad[ni];
      }
      #pragma unroll
      for (int m = 1; m < 16; m <<= 1) {
        ps += __shfl_xor(ps, m);
        pd += __shfl_xor(pd, m);
      }
      if ((lane & 15) == 0) {
        int row = rbase + mi * 16 + (kg << 2) + r;
        if (row < n) {
          s_src[(size_t)row * 4 + w] = ps;
          s_dst[(size_t)row * 4 + w] = pd;
        }
      }
    }
  }

  // epilogue A: dump acc (bf16) to swizzled LDS, then coalesced 16B stores
  #pragma unroll
  for (int mi = 0; mi < 4; ++mi)
    #pragma unroll
    for (int ni = 0; ni < 4; ++ni)
      #pragma unroll
      for (int r = 0; r < 4; ++r) {
        int row = mi * 16 + (kg << 2) + r;
        int col = (w << 6) + ni * 16 + nfix;
        int byte = row * 512 + ((col * 2) ^ (((row >> 2) & 3) << 5));
        *(unsigned short*)((char*)ols + byte) = f2bf(acc[mi][ni][r]);
      }
  __syncthreads();
  for (int c = t; c < 2048; c += 256) {
    int row = c >> 5;
    int ch  = c & 31;
    int grow = rbase + row;
    if (grow < n) {
      int byte = row * 512 + ((ch * 16) ^ (((row >> 2) & 3) << 5));
      *(uint4*)(xtb + (size_t)grow * COLS + ch * 8) =
          *(const uint4*)((const char*)ols + byte);
    }
  }
}

// ---------------------------------------------------------------------------
// CSR build: histogram -> 3-pass scan -> scatter
// ---------------------------------------------------------------------------
__global__ __launch_bounds__(256) void k_deg(const int* __restrict__ ei,
                                             int* __restrict__ deg, int E) {
  int e = blockIdx.x * 256 + threadIdx.x;
  if (e >= E) return;
  atomicAdd(&deg[ei[E + e]], 1);
}

__global__ __launch_bounds__(256) void k_scan_part(const int* __restrict__ deg,
                                                   int* __restrict__ part, int n) {
  __shared__ int wt[4];
  int i = blockIdx.x * 256 + threadIdx.x;
  int lane = threadIdx.x & 63;
  int wid = threadIdx.x >> 6;
  int v = (i < n) ? deg[i] : 0;
  #pragma unroll
  for (int m = 1; m < 64; m <<= 1) v += __shfl_xor(v, m);
  if (lane == 0) wt[wid] = v;
  __syncthreads();
  if (threadIdx.x == 0) part[blockIdx.x] = wt[0] + wt[1] + wt[2] + wt[3];
}

__global__ __launch_bounds__(256) void k_scan_top(int* __restrict__ part, int nb) {
  __shared__ int wt[4];
  int t = threadIdx.x;
  int lane = t & 63;
  int wid = t >> 6;
  int v = (t < nb) ? part[t] : 0;
  int incl = wave_incl_scan(v, lane);
  if (lane == 63) wt[wid] = incl;
  __syncthreads();
  int wofs = 0;
  #pragma unroll
  for (int w = 0; w < 4; ++w) wofs += (w < wid) ? wt[w] : 0;
  if (t < nb) part[t] = wofs + incl - v;
}

__global__ __launch_bounds__(256) void k_scan_out(const int* __restrict__ deg,
                                                  const int* __restrict__ part,
                                                  int* __restrict__ start,
                                                  int* __restrict__ cursor, int n) {
  __shared__ int wt[4];
  int i = blockIdx.x * 256 + threadIdx.x;
  int lane = threadIdx.x & 63;
  int wid = threadIdx.x >> 6;
  int v = (i < n) ? deg[i] : 0;
  int incl = wave_incl_scan(v, lane);
  if (lane == 63) wt[wid] = incl;
  __syncthreads();
  int wofs = 0;
  #pragma unroll
  for (int w = 0; w < 4; ++w) wofs += (w < wid) ? wt[w] : 0;
  int excl = part[blockIdx.x] + wofs + incl - v;
  if (i < n) { start[i] = excl; cursor[i] = excl; }
}

__global__ __launch_bounds__(256) void k_scatter(const int* __restrict__ ei,
                                                 int* __restrict__ cursor,
                                                 int* __restrict__ csr_src, int E) {
  int e = blockIdx.x * 256 + threadIdx.x;
  if (e >= E) return;
  int src = ei[e];
  int dst = ei[E + e];
  int pos = atomicAdd(&cursor[dst], 1);
  csr_src[pos] = src;
}

// ---------------------------------------------------------------------------
// K4 v2: one wave per dst node, TWO edges per iteration (32 lanes each).
// Lane g of each half covers cols g*8..g*8+7 (16B uint4 load); halves
// combined via shfl_xor(32); all 64 lanes store one float4.
// ---------------------------------------------------------------------------
__global__ __launch_bounds__(256) void k_aggr(const int* __restrict__ csr_src,
                                              const int* __restrict__ start,
                                              const int* __restrict__ deg,
                                              const float* __restrict__ s_src,
                                              const float* __restrict__ s_dst,
                                              const unsigned short* __restrict__ xtb,
                                              float* __restrict__ out, int n) {
  int node = (blockIdx.x * 256 + threadIdx.x) >> 6;
  if (node >= n) return;
  int lane = threadIdx.x & 63;
  int half = lane >> 5;       // 0 or 1
  int g    = lane & 31;
  int h    = g >> 3;          // head of this 8-lane column group
  int cbase = g << 3;         // col base 0..248

  int s = start[node];
  int e = s + deg[node];
  float sd = s_dst[node * 4 + h];

  float acc[8] = {};
  float psum = 0.f;

  int j = s + half;
  int src = (j < e) ? csr_src[j] : 0;
  while (j < e) {
    int jn = j + 2;
    int srcn = (jn < e) ? csr_src[jn] : 0;
    float v = s_src[src * 4 + h] + sd;
    v = v >= 0.f ? v : ALPHA * v;
    float p = __expf(v);
    psum += p;
    uint4 xv = *(const uint4*)(xtb + src * COLS + cbase);
    acc[0] += p * __uint_as_float(xv.x << 16);
    acc[1] += p * __uint_as_float(xv.x & 0xFFFF0000u);
    acc[2] += p * __uint_as_float(xv.y << 16);
    acc[3] += p * __uint_as_float(xv.y & 0xFFFF0000u);
    acc[4] += p * __uint_as_float(xv.z << 16);
    acc[5] += p * __uint_as_float(xv.z & 0xFFFF0000u);
    acc[6] += p * __uint_as_float(xv.w << 16);
    acc[7] += p * __uint_as_float(xv.w & 0xFFFF0000u);
    src = srcn;
    j = jn;
  }

  // combine the two edge-halves
  psum += __shfl_xor(psum, 32);
  #pragma unroll
  for (int k = 0; k < 8; ++k) acc[k] += __shfl_xor(acc[k], 32);

  float inv = 1.f / (psum + 1e-10f);
  float4 o;
  if (half) o = make_float4(acc[4] * inv, acc[5] * inv, acc[6] * inv, acc[7] * inv);
  else      o = make_float4(acc[0] * inv, acc[1] * inv, acc[2] * inv, acc[3] * inv);
  *(float4*)(out + node * COLS + cbase + half * 4) = o;
}

// ---------------------------------------------------------------------------
extern "C" void kernel_launch(void* const* d_in, const int* in_sizes, int n_in,
                              void* d_out, int out_size, void* d_ws, size_t ws_size,
                              hipStream_t stream) {
  const float* x  = (const float*)d_in[0];
  const int*   ei = (const int*)d_in[1];
  const float* W  = (const float*)d_in[2];
  const float* a  = (const float*)d_in[3];
  float* out = (float*)d_out;

  const int n = in_sizes[0] / IN_F;   // 50000
  const int E = in_sizes[1] / 2;      // 800000
  const int nb = (n + 255) / 256;     // scan blocks

  char* ws = (char*)d_ws;
  size_t off = 0;
  unsigned short* xtb = (unsigned short*)(ws + off); off += (size_t)n * COLS * 2;  // 25.6 MB
  unsigned short* Wb  = (unsigned short*)(ws + off); off += (size_t)HEADS * IN_F * OUT_F * 2;
  float* s_src = (float*)(ws + off);   off += (size_t)n * 4 * 4;
  float* s_dst = (float*)(ws + off);   off += (size_t)n * 4 * 4;
  int* deg = (int*)(ws + off);         off += (size_t)n * 4;
  int* start = (int*)(ws + off);       off += (size_t)n * 4;
  int* cursor = (int*)(ws + off);      off += (size_t)n * 4;
  int* part = (int*)(ws + off);        off += (size_t)nb * 4;
  int* csr_src = (int*)(ws + off);     off += (size_t)E * 4;

  hipMemsetAsync(deg, 0, (size_t)n * 4, stream);

  k_wconv<<<(HEADS * IN_F * OUT_F + 255) / 256, 256, 0, stream>>>(W, Wb);

  k_gemm<<<(n + 63) / 64, 256, 0, stream>>>(x, Wb, a, xtb, s_src, s_dst, n);

  k_deg<<<(E + 255) / 256, 256, 0, stream>>>(ei, deg, E);

  k_scan_part<<<nb, 256, 0, stream>>>(deg, part, n);
  k_scan_top<<<1, 256, 0, stream>>>(part, nb);
  k_scan_out<<<nb, 256, 0, stream>>>(deg, part, start, cursor, n);

  k_scatter<<<(E + 255) / 256, 256, 0, stream>>>(ei, cursor, csr_src, E);

  k_aggr<<<(n + 3) / 4, 256, 0, stream>>>(csr_src, start, deg, s_src, s_dst, xtb, out, n);
}